// Round 20
// baseline (113.550 us; speedup 1.0000x reference)
//
#include <hip/hip_runtime.h>
#include <cstdint>

#define DIM   128
#define KNN   16
#define NB    2
#define NQ    8192
#define NPTS  4096
#define KVROWS 16
#define GRID  32
#define NCELL (GRID*GRID)
#define CAP2  512

typedef unsigned short ushort_t;
typedef short vshort8 __attribute__((ext_vector_type(8)));
typedef float vfloat4 __attribute__((ext_vector_type(4)));

__device__ __forceinline__ ushort_t bf16_rne(float f) {
    unsigned u = __float_as_uint(f);
    unsigned r = u + 0x7FFFu + ((u >> 16) & 1u);
    return (ushort_t)(r >> 16);
}
__device__ __forceinline__ int cell_of(float x) {
    int c = (int)(x * 32.0f);
    return min(max(c, 0), GRID - 1);
}
__device__ __forceinline__ float f4_at(float4 v, int i) {
    return (i == 0) ? v.x : (i == 1) ? v.y : (i == 2) ? v.z : v.w;
}

// pack f32 [K][ncols] -> MFMA B-fragments (single bf16), device body
__device__ __forceinline__ void pack_body(
    const float* __restrict__ src, int K, int ncols, int NT, int KS,
    ushort_t* __restrict__ dst, int gid)
{
    int total = NT*KS*64;
    if (gid >= total) return;
    int lane = gid & 63; int c = gid >> 6;
    int s = c % KS; int n = c / KS;
    int k0 = s*32 + ((lane >> 4) << 3);
    int col = n*16 + (lane & 15);
    vshort8 v;
    #pragma unroll
    for (int i = 0; i < 8; ++i) {
        int k = k0 + i;
        float f = (k < K) ? src[k*ncols + col] : 0.f;
        v[i] = (short)bf16_rne(f);
    }
    *(vshort8*)(dst + gid*8) = v;
}

// shared 256-thread exclusive prefix over 1024 cells (4/thread)
__device__ __forceinline__ void scan1024(
    const int* __restrict__ cnt, int* __restrict__ cs, int* __restrict__ cu,
    int* __restrict__ ss, int t)
{
    int v0 = cnt[t*4 + 0];
    int v1 = cnt[t*4 + 1];
    int v2 = cnt[t*4 + 2];
    int v3 = cnt[t*4 + 3];
    int p0 = v0, p1 = p0 + v1, p2 = p1 + v2, p3 = p2 + v3;
    ss[t] = p3;
    __syncthreads();
    for (int off = 1; off < 256; off <<= 1) {
        int add = (t >= off) ? ss[t - off] : 0;
        __syncthreads();
        ss[t] += add;
        __syncthreads();
    }
    int excl = ss[t] - p3;
    cs[t*4 + 0] = excl;        cu[t*4 + 0] = excl;
    cs[t*4 + 1] = excl + p0;   cu[t*4 + 1] = excl + p0;
    cs[t*4 + 2] = excl + p1;   cu[t*4 + 2] = excl + p1;
    cs[t*4 + 3] = excl + p2;   cu[t*4 + 3] = excl + p2;
    if (t == 255) cs[NCELL] = ss[255];
}

// single-query exact kNN over ring around (cgx,cgy); deferred distances,
// extraction every round (later rounds overwrite; final round is exact).
__device__ __forceinline__ void knn_ring1(
    float xq, float yq, int cgx, int cgy,
    const float2* __restrict__ sxy_b, const int* __restrict__ sidx_b,
    const int* __restrict__ cs_b,
    float2* cxy, int* cidx, int lane, unsigned long long lmask,
    int* __restrict__ outp)
{
    const float INF = 3.4e38f, CS = 1.0f/32.0f;
    #pragma unroll 1
    for (int R = 2; R < 9; ++R) {
        int x0 = max(cgx - R, 0), x1 = min(cgx + R, GRID-1);
        int y0 = max(cgy - R, 0), y1 = min(cgy + R, GRID-1);
        int cnt = 0;
        for (int ry = y0; ry <= y1; ++ry) {
            int s0 = cs_b[ry*GRID + x0];
            int e0 = cs_b[ry*GRID + x1 + 1];
            for (int o = s0 + lane; o < e0; o += 64) {
                int slot = cnt + (o - s0);
                if (slot < CAP2) { cxy[slot] = sxy_b[o]; cidx[slot] = o; }
            }
            cnt += e0 - s0;
        }
        asm volatile("s_waitcnt lgkmcnt(0)" ::: "memory");
        __builtin_amdgcn_sched_barrier(0);
        int cc = min(cnt, CAP2);
        int kact = (cc + 63) >> 6;
        float dr[8];
        #pragma unroll
        for (int k = 0; k < 8; ++k) {
            int id = lane + k*64;
            if (id < cc) {
                float2 p = cxy[id];
                float dx = __fadd_rn(xq, -p.x);
                float dy = __fadd_rn(yq, -p.y);
                dr[k] = __fadd_rn(__fmul_rn(dx, dx), __fmul_rn(dy, dy));
            } else dr[k] = INF;
        }
        unsigned lo = 0u, hi = 0x40000000u;
        #pragma unroll 1
        for (int it = 0; it < 32; ++it) {
            if (hi - lo <= 1u) break;
            unsigned mid = (lo + hi) >> 1;
            float pv = __uint_as_float(mid);
            int c = 0;
            #pragma unroll
            for (int k = 0; k < 8; ++k)
                if (k < kact) c += __popcll(__ballot(dr[k] <= pv));
            if (c >= KNN) { hi = mid; if (c == KNN) break; }
            else lo = mid;
        }
        float thr = __uint_as_float(hi);
        int base = 0;
        #pragma unroll
        for (int k = 0; k < 8; ++k) {
            if (k < kact) {
                bool pr = dr[k] < thr;
                unsigned long long m = __ballot(pr);
                int pos = base + __popcll(m & lmask);
                if (pr && pos < KNN) outp[pos] = sidx_b[cidx[lane + k*64]];
                base += __popcll(m);
            }
        }
        #pragma unroll
        for (int k = 0; k < 8; ++k) {
            if (k < kact) {
                bool pr = dr[k] == thr;
                unsigned long long m = __ballot(pr);
                int pos = base + __popcll(m & lmask);
                if (pr && pos < KNN) outp[pos] = sidx_b[cidx[lane + k*64]];
                base += __popcll(m);
            }
        }
        float bl = (x0 > 0)      ? (xq - (float)x0*CS)     : INF;
        float br = (x1 < GRID-1) ? ((float)(x1+1)*CS - xq) : INF;
        float bb = (y0 > 0)      ? (yq - (float)y0*CS)     : INF;
        float bt = (y1 < GRID-1) ? ((float)(y1+1)*CS - yq) : INF;
        float safe = fminf(fminf(bl, br), fminf(bb, bt)) - 2e-6f;
        bool whole = (x0 == 0 && y0 == 0 && x1 == GRID-1 && y1 == GRID-1);
        if (cnt >= KNN && cnt <= CAP2 && (whole || thr <= safe*safe)) break;
    }
}

// ---------------- pre1: wprod || point-cellcount || query-cellcount.  224 x 256 ----------------
__global__ __launch_bounds__(256) void pre1_k(
    const float* __restrict__ w_ks, const float* __restrict__ g_w1,
    const float* __restrict__ pe_w, const float* __restrict__ xyz,
    const float* __restrict__ xyz_q,
    float* __restrict__ Wk1, float* __restrict__ pwc,
    int* __restrict__ cellcnt, int* __restrict__ qcnt)
{
    int t = threadIdx.x; int bx = blockIdx.x;
    if (bx < 64) {                       // Wk1
        int row = bx*2 + (t >> 7); int f = t & 127;
        float acc = 0.f;
        for (int c = 0; c < 128; ++c) acc = fmaf(w_ks[row*128 + c], g_w1[c*128 + f], acc);
        Wk1[row*128 + f] = acc;
    } else if (bx < 128) {               // pwc
        int r = bx - 64; int col = t;
        float v = 0.f;
        if (r < 33) {
            if (col < 128) {
                float a = 0.f;
                for (int c = 0; c < 128; ++c) a = fmaf(pe_w[r*128 + c], g_w1[c*128 + col], a);
                v = a;
            } else {
                v = pe_w[r*128 + (col - 128)];
            }
        }
        pwc[r*256 + col] = v;
    } else if (bx < 160) {               // point cellcount
        int gid = (bx - 128)*256 + t;
        int b = gid >> 12; int n = gid & (NPTS - 1);
        const float* p = xyz + (b*NPTS + n)*3;
        atomicAdd(&cellcnt[b*NCELL + cell_of(p[1])*GRID + cell_of(p[0])], 1);
    } else {                             // query cellcount (64 blocks)
        int gid = (bx - 160)*256 + t;
        int b = gid >> 13; int q = gid & (NQ - 1);
        const float* p = xyz_q + (b*NQ + q)*2;
        atomicAdd(&qcnt[b*NCELL + cell_of(p[1])*GRID + cell_of(p[0])], 1);
    }
}

// ---------------- pre2: packs || point-scan || query-scan || prep_global.  17 x 256 ----------------
__global__ __launch_bounds__(256) void pre2_k(
    const float* __restrict__ pwc, const float* __restrict__ g_w2,
    const int* __restrict__ cnt, const int* __restrict__ qcnt,
    const float* __restrict__ lat, const float* __restrict__ w_qs,
    const float* __restrict__ w_kg, const float* __restrict__ w_vg,
    const float* __restrict__ g_w1, const float* __restrict__ g_b1,
    const float* __restrict__ pe_b,
    ushort_t* __restrict__ pwf, ushort_t* __restrict__ w2f,
    int* __restrict__ cell_start, int* __restrict__ cursor,
    int* __restrict__ qstart, int* __restrict__ qcursor,
    float* __restrict__ c1_out, float* __restrict__ vg_out, float* __restrict__ h2g_out)
{
    __shared__ int ss[256];
    __shared__ float qs[NB][DIM];
    __shared__ float hgx[NB][DIM];
    __shared__ float h1gx[NB][DIM];
    int t = threadIdx.x; int bx = blockIdx.x;
    if (bx < 4) {
        pack_body(pwc, 32, 256, 16, 1, pwf, bx*256 + t);
    } else if (bx < 12) {
        pack_body(g_w2, 128, 128, 8, 4, w2f, (bx - 4)*256 + t);
    } else if (bx < 14) {                // point prefix, batch b
        int b = bx - 12;
        scan1024(cnt + b*NCELL, cell_start + b*(NCELL+1), cursor + b*NCELL, ss, t);
    } else if (bx < 16) {                // query prefix, batch b
        int b = bx - 14;
        scan1024(qcnt + b*NCELL, qstart + b*(NCELL+1), qcursor + b*NCELL, ss, t);
    } else {                             // prep_global
        int b = t >> 7; int f = t & 127;
        float aq = 0.f, ak = 0.f, av = 0.f;
        for (int c = 0; c < DIM; ++c) {
            float l = lat[b*DIM + c];
            aq = fmaf(l, w_qs[c*DIM + f], aq);
            ak = fmaf(l, w_kg[c*DIM + f], ak);
            av = fmaf(l, w_vg[c*DIM + f], av);
        }
        vg_out[b*DIM + f] = av;
        qs[b][f] = aq + pe_b[f];
        hgx[b][f] = aq - ak;
        __syncthreads();
        float acc = g_b1[f], acch = g_b1[f];
        for (int c = 0; c < DIM; ++c) {
            float w = g_w1[c*DIM + f];
            acc  = fmaf(qs[b][c], w, acc);
            acch = fmaf(hgx[b][c], w, acch);
        }
        c1_out[b*DIM + f] = acc;
        h1gx[b][f] = fmaxf(acch, 0.f);
        __syncthreads();
        float acc2 = 0.f;                // b2 dropped (softmax-invariant)
        for (int c = 0; c < DIM; ++c) acc2 = fmaf(h1gx[b][c], g_w2[c*DIM + f], acc2);
        h2g_out[b*DIM + f] = acc2;
    }
}

// ---------------- pre3: scatters only.  96 x 256 ----------------
__global__ __launch_bounds__(256) void pre3_k(
    const float* __restrict__ xyz, const float* __restrict__ xyz_q,
    int* __restrict__ cursor, int* __restrict__ qcursor,
    float2* __restrict__ sxy, int* __restrict__ sidx,
    float2* __restrict__ qsxy, int* __restrict__ qsidx)
{
    int t = threadIdx.x; int bx = blockIdx.x;
    if (bx < 32) {                       // point scatter
        int gid = bx*256 + t;
        int b = gid >> 12; int n = gid & (NPTS - 1);
        const float* p = xyz + (b*NPTS + n)*3;
        float x = p[0], y = p[1];
        int slot = atomicAdd(&cursor[b*NCELL + cell_of(y)*GRID + cell_of(x)], 1);
        sxy[b*NPTS + slot] = make_float2(x, y);
        sidx[b*NPTS + slot] = n;
    } else {                             // query scatter (64 blocks)
        int gid = (bx - 32)*256 + t;
        int b = gid >> 13; int q = gid & (NQ - 1);
        const float* p = xyz_q + (b*NQ + q)*2;
        float x = p[0], y = p[1];
        int slot = atomicAdd(&qcursor[b*NCELL + cell_of(y)*GRID + cell_of(x)], 1);
        qsxy[b*NQ + slot] = make_float2(x, y);
        qsidx[b*NQ + slot] = q;
    }
}

// ---------------- knn+kv co-scheduled.  (512 + 1024) x 256 ----------------
// bx < 512: kv_proj (fragment-major K1c/Vp, c1 folded).
// bx >= 512: exact kNN, 4 sorted queries per WAVE with ONE shared candidate
// gather (union ring); per-query rank-select against the shared pool.
__global__ __launch_bounds__(256) void knnkv_k(
    const float* __restrict__ points, const float* __restrict__ Wk1,
    const float* __restrict__ w_vs, const float* __restrict__ pe_b,
    const float* __restrict__ c1_,
    const float2* __restrict__ qsxy, const float2* __restrict__ sxy,
    const int* __restrict__ sidx, const int* __restrict__ cstart,
    float* __restrict__ K1c, float* __restrict__ Vp,
    int* __restrict__ knn_out)
{
    __shared__ __align__(16) float smem[6144];       // 24 KB overlay
    int t = threadIdx.x; int bx = blockIdx.x;

    if (bx < 512) {
        // ---------------- kv_proj (round-19 exact) ----------------
        float* pts = smem;                           // 8 KB
        int r0 = bx * KVROWS;
        int b = r0 >> 12;
        #pragma unroll
        for (int k = 0; k < KVROWS*DIM/256; ++k) {
            int e = t + k*256;
            pts[e] = points[r0*DIM + e];
        }
        __syncthreads();
        int f = t & 127; int mat = t >> 7;
        const float* W = mat ? w_vs : Wk1;
        float* O = mat ? Vp : K1c;
        float addv = mat ? pe_b[f] : c1_[b*DIM + f];
        float sgn  = mat ? 1.f : -1.f;
        int fc = (f & 15)*8 + (f >> 4);              // fragment-major position
        float acc[KVROWS];
        #pragma unroll
        for (int r = 0; r < KVROWS; ++r) acc[r] = 0.f;
        const float4* pts4 = reinterpret_cast<const float4*>(pts);
        for (int c4 = 0; c4 < DIM/4; ++c4) {
            float w0 = W[(c4*4+0)*DIM + f];
            float w1 = W[(c4*4+1)*DIM + f];
            float w2 = W[(c4*4+2)*DIM + f];
            float w3 = W[(c4*4+3)*DIM + f];
            #pragma unroll
            for (int r = 0; r < KVROWS; ++r) {
                float4 p = pts4[r*(DIM/4) + c4];
                acc[r] = fmaf(p.x, w0, acc[r]);
                acc[r] = fmaf(p.y, w1, acc[r]);
                acc[r] = fmaf(p.z, w2, acc[r]);
                acc[r] = fmaf(p.w, w3, acc[r]);
            }
        }
        #pragma unroll
        for (int r = 0; r < KVROWS; ++r) O[(r0 + r)*DIM + fc] = fmaf(sgn, acc[r], addv);
        return;
    }

    // ---------------- exact kNN, 4 queries/wave ----------------
    int bxk = bx - 512;
    int wid = t >> 6, lane = t & 63;
    int b = bxk >> 9; int qg = (bxk & 511)*16 + wid*4;
    float2* cxy = (float2*)smem + wid*CAP2;              // 16 KB total
    int*    cidx = (int*)(smem + 4096) + wid*CAP2;       // 8 KB total
    const float2* sxy_b = sxy + b*NPTS;
    const int* sidx_b = sidx + b*NPTS;
    const int* cs_b = cstart + b*(NCELL+1);
    const float INF = 3.4e38f, CS = 1.0f/32.0f;
    unsigned long long lmask = (1ull << lane) - 1ull;

    float xq[4], yq[4]; int cxi[4], cyi[4];
    #pragma unroll
    for (int i = 0; i < 4; ++i) {
        float2 qp = qsxy[b*NQ + qg + i];
        xq[i] = qp.x; yq[i] = qp.y;
        cxi[i] = cell_of(qp.x); cyi[i] = cell_of(qp.y);
    }
    int x0g = min(min(cxi[0], cxi[1]), min(cxi[2], cxi[3]));
    int x1g = max(max(cxi[0], cxi[1]), max(cxi[2], cxi[3]));
    int y0g = min(min(cyi[0], cyi[1]), min(cyi[2], cyi[3]));
    int y1g = max(max(cyi[0], cyi[1]), max(cyi[2], cyi[3]));

    if (x1g - x0g <= 3 && y1g - y0g <= 3) {
        // shared-gather fast path
        #pragma unroll 1
        for (int R = 2; R < 9; ++R) {
            int x0 = max(x0g - R, 0), x1 = min(x1g + R, GRID-1);
            int y0 = max(y0g - R, 0), y1 = min(y1g + R, GRID-1);
            int cnt = 0;
            for (int ry = y0; ry <= y1; ++ry) {
                int s0 = cs_b[ry*GRID + x0];
                int e0 = cs_b[ry*GRID + x1 + 1];
                for (int o = s0 + lane; o < e0; o += 64) {
                    int slot = cnt + (o - s0);
                    if (slot < CAP2) { cxy[slot] = sxy_b[o]; cidx[slot] = o; }
                }
                cnt += e0 - s0;
            }
            asm volatile("s_waitcnt lgkmcnt(0)" ::: "memory");
            __builtin_amdgcn_sched_barrier(0);

            int cc = min(cnt, CAP2);
            int kact = (cc + 63) >> 6;
            bool whole = (x0 == 0 && y0 == 0 && x1 == GRID-1 && y1 == GRID-1);
            bool okv[4];
            #pragma unroll
            for (int i = 0; i < 4; ++i) {
                float dr[8];
                #pragma unroll
                for (int k = 0; k < 8; ++k) {
                    int id = lane + k*64;
                    if (id < cc) {
                        float2 p = cxy[id];
                        float dx = __fadd_rn(xq[i], -p.x);
                        float dy = __fadd_rn(yq[i], -p.y);
                        dr[k] = __fadd_rn(__fmul_rn(dx, dx), __fmul_rn(dy, dy));
                    } else dr[k] = INF;
                }
                unsigned lo = 0u, hi = 0x40000000u;
                #pragma unroll 1
                for (int it = 0; it < 32; ++it) {
                    if (hi - lo <= 1u) break;
                    unsigned mid = (lo + hi) >> 1;
                    float pv = __uint_as_float(mid);
                    int c = 0;
                    #pragma unroll
                    for (int k = 0; k < 8; ++k)
                        if (k < kact) c += __popcll(__ballot(dr[k] <= pv));
                    if (c >= KNN) { hi = mid; if (c == KNN) break; }
                    else lo = mid;
                }
                float thr = __uint_as_float(hi);
                int* outp = knn_out + (b*NQ + qg + i)*KNN;
                int base = 0;
                #pragma unroll
                for (int k = 0; k < 8; ++k) {
                    if (k < kact) {
                        bool pr = dr[k] < thr;
                        unsigned long long m = __ballot(pr);
                        int pos = base + __popcll(m & lmask);
                        if (pr && pos < KNN) outp[pos] = sidx_b[cidx[lane + k*64]];
                        base += __popcll(m);
                    }
                }
                #pragma unroll
                for (int k = 0; k < 8; ++k) {
                    if (k < kact) {
                        bool pr = dr[k] == thr;
                        unsigned long long m = __ballot(pr);
                        int pos = base + __popcll(m & lmask);
                        if (pr && pos < KNN) outp[pos] = sidx_b[cidx[lane + k*64]];
                        base += __popcll(m);
                    }
                }
                float bl = (x0 > 0)      ? (xq[i] - (float)x0*CS)     : INF;
                float br = (x1 < GRID-1) ? ((float)(x1+1)*CS - xq[i]) : INF;
                float bb = (y0 > 0)      ? (yq[i] - (float)y0*CS)     : INF;
                float bt = (y1 < GRID-1) ? ((float)(y1+1)*CS - yq[i]) : INF;
                float safe = fminf(fminf(bl, br), fminf(bb, bt)) - 2e-6f;
                okv[i] = (cnt >= KNN) && (cnt <= CAP2) && (whole || thr <= safe*safe);
            }
            if ((okv[0] && okv[1] && okv[2] && okv[3]) || R == 8) break;
        }
    } else {
        // rare fallback (row-wrap groups): per-query rings
        #pragma unroll
        for (int i = 0; i < 4; ++i) {
            knn_ring1(xq[i], yq[i], cxi[i], cyi[i], sxy_b, sidx_b, cs_b,
                      cxy, cidx, lane, lmask,
                      knn_out + (b*NQ + qg + i)*KNN);
        }
    }
}

// ---------------- fused MFMA kernel (round-19 exact) ----------------
__global__ __launch_bounds__(512, 2) void fuse_k(
    const float2* __restrict__ qsxy, const int* __restrict__ qsidx,
    const float* __restrict__ xyz,
    const float* __restrict__ K1c, const float* __restrict__ Vp,
    const int* __restrict__ knn_idx,
    const float* __restrict__ vg_, const float* __restrict__ h2g_,
    const float* __restrict__ pw32_,
    const ushort_t* __restrict__ pwf, const ushort_t* __restrict__ w2f,
    float* __restrict__ out)
{
    __shared__ __align__(16) ushort_t w2B[32*512];   // 32 KB
    __shared__ __align__(16) ushort_t h1b[8][2048];  // 32 KB (single bf16, per-wave)

    int t = threadIdx.x, lane = t & 63, wid = t >> 6;
    // bijective XCD swizzle over 512 blocks
    int sid = (blockIdx.x & 7) * 64 + (blockIdx.x >> 3);
    int b = sid >> 8; int qbase = (sid & 255) * 32;

    {   // stage w2 frags once per block (32 KB)
        const int4* s2 = (const int4*)w2f;  int4* d2 = (int4*)w2B;
        #pragma unroll
        for (int i = 0; i < 4; ++i) d2[t + i*512] = s2[t + i*512];
    }
    __syncthreads();

    int c16 = lane & 15, g = lane >> 4, rowbase = g*4;
    ushort_t* hb = h1b[wid];
    const vshort8* pwBv = (const vshort8*)pwf;       // global, L1-resident
    const vshort8* w2Bv = (const vshort8*)w2B;
    const float4* K4 = (const float4*)K1c;
    const float4* V4 = (const float4*)Vp;
    const vfloat4 vzero = (vfloat4){0.f, 0.f, 0.f, 0.f};

    // query-invariant hoists (per-lane): 32 regs
    float pw32r[16], hgr[8], vgr[8];
    #pragma unroll
    for (int n = 0; n < 16; ++n) pw32r[n] = pw32_[n*16 + c16];
    #pragma unroll
    for (int n = 0; n < 8; ++n) {
        hgr[n] = h2g_[b*128 + n*16 + c16];
        vgr[n] = vg_[b*128 + n*16 + c16];
    }

    #pragma unroll 1
    for (int qi = 0; qi < 4; ++qi) {
        int q = qbase + wid*4 + qi;                  // sorted index
        float2 qp = qsxy[b*NQ + q];
        float xq = qp.x, yq = qp.y;
        int qorig = qsidx[b*NQ + q];
        int idxrow = knn_idx[(b*NQ + q)*KNN + c16];
        const float* p = xyz + (b*NPTS + idxrow)*3;
        float pd0 = xq - p[0], pd1 = yq - p[1], pd2 = p[2];
        int rf4[4];   // float4 base index of this lane's span in its 4 C-rows
        #pragma unroll
        for (int r = 0; r < 4; ++r)
            rf4[r] = (b*NPTS + __shfl(idxrow, rowbase + r))*32 + c16*2;

        // emb A-fragment in registers: k = g*8 + j
        vshort8 eh;
        int k0 = g*8;
        #pragma unroll
        for (int j = 0; j < 8; ++j) {
            int k = k0 + j;
            float v;
            if (k < 3) {
                v = (k == 0) ? pd0 : (k == 1 ? pd1 : pd2);
            } else {
                int m = k - 3; int fi = m / 6; int rem = m - fi*6;
                int comp = (rem < 3) ? rem : rem - 3;
                float pdc = (comp == 0) ? pd0 : (comp == 1 ? pd1 : pd2);
                float fr = (fi == 0) ? 1.0f : (fi == 1) ? 8.75f : (fi == 2) ? 16.5f
                         : (fi == 3) ? 24.25f : 32.0f;
                float arg = pdc * fr;
                v = (rem < 3) ? __sinf(arg) : __cosf(arg);
            }
            eh[j] = (short)bf16_rne(v);
        }
        float c32 = __cosf(32.0f * pd2);
        float c32r[4];
        #pragma unroll
        for (int r = 0; r < 4; ++r) c32r[r] = __shfl(c32, rowbase + r);

        // pe1 + h1 epilogue in two half-batches; K1c gathers are float4
        #pragma unroll
        for (int half = 0; half < 2; ++half) {
            float4 k1q[4];
            #pragma unroll
            for (int r = 0; r < 4; ++r) k1q[r] = K4[rf4[r] + half];
            #pragma unroll
            for (int nn = 0; nn < 4; ++nn) {
                int n = half*4 + nn;
                vfloat4 a = __builtin_amdgcn_mfma_f32_16x16x32_bf16(
                    eh, pwBv[n*64 + lane], vzero, 0, 0, 0);
                int col = n*16 + c16;
                int s = col >> 5;
                int lp = ((col >> 3) & 3) << 4;
                int j = c16 & 7;
                #pragma unroll
                for (int r = 0; r < 4; ++r) {
                    float h = f4_at(k1q[r], nn) + fmaf(c32r[r], pw32r[n], a[r]);
                    h = fmaxf(h, 0.f);
                    hb[s*512 + (lp | (rowbase + r))*8 + j] = bf16_rne(h);
                }
            }
        }
        asm volatile("s_waitcnt lgkmcnt(0)" ::: "memory");
        __builtin_amdgcn_sched_barrier(0);

        // GEMM2: [16x128]@[128x128], single bf16
        vfloat4 acc2[8];
        #pragma unroll
        for (int n = 0; n < 8; ++n) acc2[n] = vzero;
        #pragma unroll
        for (int s = 0; s < 4; ++s) {
            vshort8 ah = ((const vshort8*)hb)[s*64 + lane];
            #pragma unroll
            for (int n = 0; n < 8; ++n) {
                vshort8 bh = w2Bv[(n*4 + s)*64 + lane];
                acc2[n] = __builtin_amdgcn_mfma_f32_16x16x32_bf16(ah, bh, acc2[n], 0, 0, 0);
            }
        }

        // softmax over 17 slots, pe2 per-n; Vp gathers are float4 per half-batch
        #pragma unroll
        for (int half = 0; half < 2; ++half) {
            float4 vq[4];
            #pragma unroll
            for (int r = 0; r < 4; ++r) vq[r] = V4[rf4[r] + half];
            #pragma unroll
            for (int nn = 0; nn < 4; ++nn) {
                int n = half*4 + nn;
                vfloat4 ap = __builtin_amdgcn_mfma_f32_16x16x32_bf16(
                    eh, pwBv[(8 + n)*64 + lane], vzero, 0, 0, 0);
                #pragma unroll
                for (int r = 0; r < 4; ++r) ap[r] = fmaf(c32r[r], pw32r[8 + n], ap[r]);

                float hg = hgr[n];
                vfloat4 a2 = acc2[n];
                float mx = fmaxf(fmaxf(a2[0], a2[1]), fmaxf(a2[2], a2[3]));
                mx = fmaxf(mx, __shfl_xor(mx, 16));
                mx = fmaxf(mx, __shfl_xor(mx, 32));
                mx = fmaxf(mx, hg);
                float sum = 0.f, num = 0.f;
                #pragma unroll
                for (int r = 0; r < 4; ++r) {
                    float ev = __expf(a2[r] - mx);
                    float v = f4_at(vq[r], nn) + ap[r];
                    sum += ev;
                    num = fmaf(ev, v, num);
                }
                sum += __shfl_xor(sum, 16); sum += __shfl_xor(sum, 32);
                num += __shfl_xor(num, 16); num += __shfl_xor(num, 32);
                float eg = __expf(hg - mx);
                sum += eg;
                num = fmaf(eg, vgr[n], num);
                if (g == 0) out[(b*NQ + qorig)*128 + n*16 + c16] = num / sum;
            }
        }
    }
}

extern "C" void kernel_launch(void* const* d_in, const int* in_sizes, int n_in,
                              void* d_out, int out_size, void* d_ws, size_t ws_size,
                              hipStream_t stream) {
    const float* xyz_q  = (const float*)d_in[0];
    const float* lat    = (const float*)d_in[1];
    const float* xyz    = (const float*)d_in[2];
    const float* points = (const float*)d_in[3];
    const float* w_qs   = (const float*)d_in[4];
    const float* w_ks   = (const float*)d_in[5];
    const float* w_vs   = (const float*)d_in[6];
    const float* w_kg   = (const float*)d_in[7];
    const float* w_vg   = (const float*)d_in[8];
    const float* g_w1   = (const float*)d_in[9];
    const float* g_b1   = (const float*)d_in[10];
    const float* g_w2   = (const float*)d_in[11];
    const float* g_b2   = (const float*)d_in[12];  // cancels under softmax
    const float* pe_w   = (const float*)d_in[13];
    const float* pe_b   = (const float*)d_in[14];
    float* out = (float*)d_out;
    (void)g_b2;

    float* ws   = (float*)d_ws;
    float* Vp   = ws;                          // 2*4096*128
    float* K1c  = Vp  + NB*NPTS*DIM;           // 2*4096*128
    float* Wk1  = K1c + NB*NPTS*DIM;           // 128*128
    float* pwc  = Wk1 + DIM*DIM;               // 64*256
    float* c1   = pwc + 64*256;                // 256
    float* vg   = c1  + NB*DIM;                // 256
    float* h2g  = vg  + NB*DIM;                // 256
    int*   knn  = (int*)(h2g + NB*DIM);        // 2*8192*16
    ushort_t* pwf = (ushort_t*)(knn + NB*NQ*KNN);   // 16 KB
    ushort_t* w2f = pwf + 16*64*8;                  // 32 KB
    int* cellcnt  = (int*)(w2f + 32*64*8);          // 2*1024   (zeroed)
    int* qcnt     = cellcnt + NB*NCELL;             // 2*1024   (zeroed, adjacent)
    int* cellstart = qcnt + NB*NCELL;               // 2*1025
    int* cursor    = cellstart + NB*(NCELL+1);      // 2*1024
    int* qstart    = cursor + NB*NCELL;             // 2*1025
    int* qcursor   = qstart + NB*(NCELL+1);         // 2*1024
    int* sidx      = qcursor + NB*NCELL;            // 2*4096
    float2* sxy    = (float2*)(sidx + NB*NPTS);     // 2*4096 float2
    int* qsidx     = (int*)(sxy + NB*NPTS);         // 2*8192
    float2* qsxy   = (float2*)(qsidx + NB*NQ);      // 2*8192 float2

    hipMemsetAsync(cellcnt, 0, 2*NB*NCELL*sizeof(int), stream);  // cellcnt + qcnt
    pre1_k<<<224, 256, 0, stream>>>(w_ks, g_w1, pe_w, xyz, xyz_q,
                                    Wk1, pwc, cellcnt, qcnt);
    pre2_k<<<17, 256, 0, stream>>>(pwc, g_w2, cellcnt, qcnt,
                                   lat, w_qs, w_kg, w_vg, g_w1, g_b1, pe_b,
                                   pwf, w2f, cellstart, cursor, qstart, qcursor,
                                   c1, vg, h2g);
    pre3_k<<<96, 256, 0, stream>>>(xyz, xyz_q, cursor, qcursor,
                                   sxy, sidx, qsxy, qsidx);
    knnkv_k<<<512 + NB*NQ/16, 256, 0, stream>>>(points, Wk1, w_vs, pe_b, c1,
                                                qsxy, sxy, sidx, cellstart,
                                                K1c, Vp, knn);
    fuse_k<<<NB*NQ/32, 512, 0, stream>>>(qsxy, qsidx, xyz, K1c, Vp, knn, vg, h2g,
                                         pwc + 32*256, pwf, w2f, out);
}

// Round 21
// 109.634 us; speedup vs baseline: 1.0357x; 1.0357x over previous
//
#include <hip/hip_runtime.h>
#include <cstdint>

#define DIM   128
#define KNN   16
#define NB    2
#define NQ    8192
#define NPTS  4096
#define KVROWS 16
#define GRID  32
#define NCELL (GRID*GRID)
#define CAP   384

typedef unsigned short ushort_t;
typedef short vshort8 __attribute__((ext_vector_type(8)));
typedef float vfloat4 __attribute__((ext_vector_type(4)));

__device__ __forceinline__ ushort_t bf16_rne(float f) {
    unsigned u = __float_as_uint(f);
    unsigned r = u + 0x7FFFu + ((u >> 16) & 1u);
    return (ushort_t)(r >> 16);
}
__device__ __forceinline__ int cell_of(float x) {
    int c = (int)(x * 32.0f);
    return min(max(c, 0), GRID - 1);
}

// pack f32 [K][ncols] -> MFMA B-fragments (single bf16), device body
__device__ __forceinline__ void pack_body(
    const float* __restrict__ src, int K, int ncols, int NT, int KS,
    ushort_t* __restrict__ dst, int gid)
{
    int total = NT*KS*64;
    if (gid >= total) return;
    int lane = gid & 63; int c = gid >> 6;
    int s = c % KS; int n = c / KS;
    int k0 = s*32 + ((lane >> 4) << 3);
    int col = n*16 + (lane & 15);
    vshort8 v;
    #pragma unroll
    for (int i = 0; i < 8; ++i) {
        int k = k0 + i;
        float f = (k < K) ? src[k*ncols + col] : 0.f;
        v[i] = (short)bf16_rne(f);
    }
    *(vshort8*)(dst + gid*8) = v;
}

// shared 256-thread exclusive prefix over 1024 cells (4/thread)
__device__ __forceinline__ void scan1024(
    const int* __restrict__ cnt, int* __restrict__ cs, int* __restrict__ cu,
    int* __restrict__ ss, int t)
{
    int v0 = cnt[t*4 + 0];
    int v1 = cnt[t*4 + 1];
    int v2 = cnt[t*4 + 2];
    int v3 = cnt[t*4 + 3];
    int p0 = v0, p1 = p0 + v1, p2 = p1 + v2, p3 = p2 + v3;
    ss[t] = p3;
    __syncthreads();
    for (int off = 1; off < 256; off <<= 1) {
        int add = (t >= off) ? ss[t - off] : 0;
        __syncthreads();
        ss[t] += add;
        __syncthreads();
    }
    int excl = ss[t] - p3;
    cs[t*4 + 0] = excl;        cu[t*4 + 0] = excl;
    cs[t*4 + 1] = excl + p0;   cu[t*4 + 1] = excl + p0;
    cs[t*4 + 2] = excl + p1;   cu[t*4 + 2] = excl + p1;
    cs[t*4 + 3] = excl + p2;   cu[t*4 + 3] = excl + p2;
    if (t == 255) cs[NCELL] = ss[255];
}

// ---------------- pre1: wprod || point-cellcount || query-cellcount.  224 x 256 ----------------
__global__ __launch_bounds__(256) void pre1_k(
    const float* __restrict__ w_ks, const float* __restrict__ g_w1,
    const float* __restrict__ pe_w, const float* __restrict__ xyz,
    const float* __restrict__ xyz_q,
    float* __restrict__ Wk1, float* __restrict__ pwc,
    int* __restrict__ cellcnt, int* __restrict__ qcnt)
{
    int t = threadIdx.x; int bx = blockIdx.x;
    if (bx < 64) {                       // Wk1
        int row = bx*2 + (t >> 7); int f = t & 127;
        float acc = 0.f;
        for (int c = 0; c < 128; ++c) acc = fmaf(w_ks[row*128 + c], g_w1[c*128 + f], acc);
        Wk1[row*128 + f] = acc;
    } else if (bx < 128) {               // pwc
        int r = bx - 64; int col = t;
        float v = 0.f;
        if (r < 33) {
            if (col < 128) {
                float a = 0.f;
                for (int c = 0; c < 128; ++c) a = fmaf(pe_w[r*128 + c], g_w1[c*128 + col], a);
                v = a;
            } else {
                v = pe_w[r*128 + (col - 128)];
            }
        }
        pwc[r*256 + col] = v;
    } else if (bx < 160) {               // point cellcount
        int gid = (bx - 128)*256 + t;
        int b = gid >> 12; int n = gid & (NPTS - 1);
        const float* p = xyz + (b*NPTS + n)*3;
        atomicAdd(&cellcnt[b*NCELL + cell_of(p[1])*GRID + cell_of(p[0])], 1);
    } else {                             // query cellcount (64 blocks)
        int gid = (bx - 160)*256 + t;
        int b = gid >> 13; int q = gid & (NQ - 1);
        const float* p = xyz_q + (b*NQ + q)*2;
        atomicAdd(&qcnt[b*NCELL + cell_of(p[1])*GRID + cell_of(p[0])], 1);
    }
}

// ---------------- pre2: packs || point-scan || query-scan || prep_global.  17 x 256 ----------------
__global__ __launch_bounds__(256) void pre2_k(
    const float* __restrict__ pwc, const float* __restrict__ g_w2,
    const int* __restrict__ cnt, const int* __restrict__ qcnt,
    const float* __restrict__ lat, const float* __restrict__ w_qs,
    const float* __restrict__ w_kg, const float* __restrict__ w_vg,
    const float* __restrict__ g_w1, const float* __restrict__ g_b1,
    const float* __restrict__ pe_b,
    ushort_t* __restrict__ pwf, ushort_t* __restrict__ w2f,
    int* __restrict__ cell_start, int* __restrict__ cursor,
    int* __restrict__ qstart, int* __restrict__ qcursor,
    float* __restrict__ c1_out, float* __restrict__ vg_out, float* __restrict__ h2g_out)
{
    __shared__ int ss[256];
    __shared__ float qs[NB][DIM];
    __shared__ float hgx[NB][DIM];
    __shared__ float h1gx[NB][DIM];
    int t = threadIdx.x; int bx = blockIdx.x;
    if (bx < 4) {
        pack_body(pwc, 32, 256, 16, 1, pwf, bx*256 + t);
    } else if (bx < 12) {
        pack_body(g_w2, 128, 128, 8, 4, w2f, (bx - 4)*256 + t);
    } else if (bx < 14) {                // point prefix, batch b
        int b = bx - 12;
        scan1024(cnt + b*NCELL, cell_start + b*(NCELL+1), cursor + b*NCELL, ss, t);
    } else if (bx < 16) {                // query prefix, batch b
        int b = bx - 14;
        scan1024(qcnt + b*NCELL, qstart + b*(NCELL+1), qcursor + b*NCELL, ss, t);
    } else {                             // prep_global
        int b = t >> 7; int f = t & 127;
        float aq = 0.f, ak = 0.f, av = 0.f;
        for (int c = 0; c < DIM; ++c) {
            float l = lat[b*DIM + c];
            aq = fmaf(l, w_qs[c*DIM + f], aq);
            ak = fmaf(l, w_kg[c*DIM + f], ak);
            av = fmaf(l, w_vg[c*DIM + f], av);
        }
        vg_out[b*DIM + f] = av;
        qs[b][f] = aq + pe_b[f];
        hgx[b][f] = aq - ak;
        __syncthreads();
        float acc = g_b1[f], acch = g_b1[f];
        for (int c = 0; c < DIM; ++c) {
            float w = g_w1[c*DIM + f];
            acc  = fmaf(qs[b][c], w, acc);
            acch = fmaf(hgx[b][c], w, acch);
        }
        c1_out[b*DIM + f] = acc;
        h1gx[b][f] = fmaxf(acch, 0.f);
        __syncthreads();
        float acc2 = 0.f;                // b2 dropped (softmax-invariant)
        for (int c = 0; c < DIM; ++c) acc2 = fmaf(h1gx[b][c], g_w2[c*DIM + f], acc2);
        h2g_out[b*DIM + f] = acc2;
    }
}

// ---------------- pre3: kv_proj || point-scatter || query-scatter.  608 x 256 ----------------
__global__ __launch_bounds__(256) void pre3_k(
    const float* __restrict__ points, const float* __restrict__ Wk1,
    const float* __restrict__ w_vs, const float* __restrict__ pe_b,
    const float* __restrict__ xyz, const float* __restrict__ xyz_q,
    int* __restrict__ cursor, int* __restrict__ qcursor,
    float* __restrict__ K1p, float* __restrict__ Vp,
    float2* __restrict__ sxy, int* __restrict__ sidx,
    float2* __restrict__ qsxy, int* __restrict__ qsidx)
{
    __shared__ __align__(16) float pts[KVROWS*DIM];
    int t = threadIdx.x; int bx = blockIdx.x;
    if (bx < 512) {                      // kv_proj (round-7 exact math)
        int r0 = bx * KVROWS;
        #pragma unroll
        for (int k = 0; k < KVROWS*DIM/256; ++k) {
            int e = t + k*256;
            pts[e] = points[r0*DIM + e];
        }
        __syncthreads();
        int f = t & 127; int mat = t >> 7;
        const float* W = mat ? w_vs : Wk1;
        float* O = mat ? Vp : K1p;
        float addv = mat ? pe_b[f] : 0.f;
        float acc[KVROWS];
        #pragma unroll
        for (int r = 0; r < KVROWS; ++r) acc[r] = 0.f;
        const float4* pts4 = reinterpret_cast<const float4*>(pts);
        for (int c4 = 0; c4 < DIM/4; ++c4) {
            float w0 = W[(c4*4+0)*DIM + f];
            float w1 = W[(c4*4+1)*DIM + f];
            float w2 = W[(c4*4+2)*DIM + f];
            float w3 = W[(c4*4+3)*DIM + f];
            #pragma unroll
            for (int r = 0; r < KVROWS; ++r) {
                float4 p = pts4[r*(DIM/4) + c4];
                acc[r] = fmaf(p.x, w0, acc[r]);
                acc[r] = fmaf(p.y, w1, acc[r]);
                acc[r] = fmaf(p.z, w2, acc[r]);
                acc[r] = fmaf(p.w, w3, acc[r]);
            }
        }
        #pragma unroll
        for (int r = 0; r < KVROWS; ++r) O[(r0 + r)*DIM + f] = acc[r] + addv;
    } else if (bx < 544) {               // point scatter
        int gid = (bx - 512)*256 + t;
        int b = gid >> 12; int n = gid & (NPTS - 1);
        const float* p = xyz + (b*NPTS + n)*3;
        float x = p[0], y = p[1];
        int slot = atomicAdd(&cursor[b*NCELL + cell_of(y)*GRID + cell_of(x)], 1);
        sxy[b*NPTS + slot] = make_float2(x, y);
        sidx[b*NPTS + slot] = n;
    } else {                             // query scatter (64 blocks)
        int gid = (bx - 544)*256 + t;
        int b = gid >> 13; int q = gid & (NQ - 1);
        const float* p = xyz_q + (b*NQ + q)*2;
        float x = p[0], y = p[1];
        int slot = atomicAdd(&qcursor[b*NCELL + cell_of(y)*GRID + cell_of(x)], 1);
        qsxy[b*NQ + slot] = make_float2(x, y);
        qsidx[b*NQ + slot] = q;
    }
}

// ---------------- exact kNN: ballot rank-select over sorted queries ----------------
__global__ __launch_bounds__(256) void knn_k(
    const float2* __restrict__ qsxy, const float2* __restrict__ sxy,
    const int* __restrict__ sidx, const int* __restrict__ cstart,
    int* __restrict__ knn_out)
{
    __shared__ float cand_d[4][CAP];
    __shared__ int   cand_i[4][CAP];
    int t = threadIdx.x; int wid = t >> 6, lane = t & 63;
    int bx = blockIdx.x; int b = bx >> 11; int q = (bx & 2047)*4 + wid;
    float2 qp = qsxy[b*NQ + q];
    float xq = qp.x, yq = qp.y;
    int cx = cell_of(xq), cy = cell_of(yq);
    const int* cs_b = cstart + b*(NCELL+1);
    float* cd = cand_d[wid]; int* ci = cand_i[wid];
    const float INF = 3.4e38f;
    const float CS = 1.0f/32.0f;
    int* outp = knn_out + (b*NQ + q)*KNN;
    unsigned long long lmask = (1ull << lane) - 1ull;

    for (int R = 2; R < 9; ++R) {
        int x0 = max(cx-R, 0), x1 = min(cx+R, GRID-1);
        int y0 = max(cy-R, 0), y1 = min(cy+R, GRID-1);
        int cnt = 0;
        for (int ry = y0; ry <= y1; ++ry) {
            int s0 = cs_b[ry*GRID + x0];
            int e0 = cs_b[ry*GRID + x1 + 1];
            for (int o = s0 + lane; o < e0; o += 64) {
                float2 p = sxy[b*NPTS + o];
                float dx = __fadd_rn(xq, -p.x);
                float dy = __fadd_rn(yq, -p.y);
                float d = __fadd_rn(__fmul_rn(dx, dx), __fmul_rn(dy, dy));
                int slot = cnt + (o - s0);
                if (slot < CAP) { cd[slot] = d; ci[slot] = o; }
            }
            cnt += e0 - s0;
        }
        asm volatile("s_waitcnt lgkmcnt(0)" ::: "memory");
        __builtin_amdgcn_sched_barrier(0);

        int cc = min(cnt, CAP);
        float dr[6];
        #pragma unroll
        for (int k = 0; k < 6; ++k)
            dr[k] = (lane + k*64 < cc) ? cd[lane + k*64] : INF;

        unsigned lo = 0u, hi = 0x40000000u;   // 2.0f
        #pragma unroll 1
        for (int it = 0; it < 32; ++it) {
            if (hi - lo <= 1u) break;
            unsigned mid = (lo + hi) >> 1;
            float pv = __uint_as_float(mid);
            int c = 0;
            #pragma unroll
            for (int k = 0; k < 6; ++k)
                c += __popcll(__ballot(dr[k] <= pv));
            if (c >= KNN) {
                hi = mid;
                if (c == KNN) break;
            } else {
                lo = mid;
            }
        }
        float thr = __uint_as_float(hi);     // thr in [d16, d17)

        float bl = (x0 > 0)      ? (xq - (float)x0*CS)       : INF;
        float br = (x1 < GRID-1) ? ((float)(x1+1)*CS - xq)   : INF;
        float bb = (y0 > 0)      ? (yq - (float)y0*CS)       : INF;
        float bt = (y1 < GRID-1) ? ((float)(y1+1)*CS - yq)   : INF;
        float safe = fminf(fminf(bl, br), fminf(bb, bt)) - 2e-6f;
        bool whole = (safe > 1e8f);
        bool ok = (cnt >= KNN) && (cnt <= CAP) && (whole || thr <= safe*safe);
        if (ok || R == 8) {
            int base = 0;
            #pragma unroll
            for (int k = 0; k < 6; ++k) {
                bool p = dr[k] < thr;
                unsigned long long m = __ballot(p);
                int pos = base + __popcll(m & lmask);
                if (p && pos < KNN) outp[pos] = sidx[b*NPTS + ci[lane + k*64]];
                base += __popcll(m);
            }
            #pragma unroll
            for (int k = 0; k < 6; ++k) {
                bool p = dr[k] == thr;
                unsigned long long m = __ballot(p);
                int pos = base + __popcll(m & lmask);
                if (p && pos < KNN) outp[pos] = sidx[b*NPTS + ci[lane + k*64]];
                base += __popcll(m);
            }
            break;
        }
    }
}

// ---------------- fused MFMA kernel (round-14 body; trailing fence removed) ----------------
// 512 thr / 8 waves, UNCAPPED (2 waves/SIMD is this body's register ceiling; any
// launch_bounds cap makes hipcc halve the arch-VGPR budget and spill).
__global__ __launch_bounds__(512, 2) void fuse_k(
    const float2* __restrict__ qsxy, const int* __restrict__ qsidx,
    const float* __restrict__ xyz,
    const float* __restrict__ K1p, const float* __restrict__ Vp,
    const int* __restrict__ knn_idx,
    const float* __restrict__ c1_, const float* __restrict__ vg_,
    const float* __restrict__ h2g_, const float* __restrict__ pw32_,
    const ushort_t* __restrict__ pwf, const ushort_t* __restrict__ w2f,
    float* __restrict__ out)
{
    __shared__ __align__(16) ushort_t w2B[32*512];   // 32 KB
    __shared__ __align__(16) ushort_t h1b[8][2048];  // 32 KB (single bf16, per-wave)

    int t = threadIdx.x, lane = t & 63, wid = t >> 6;
    // bijective XCD swizzle over 512 blocks: each XCD gets a contiguous
    // 64-block (2048 sorted-query) spatial slice -> K1p/Vp slice L2-resident.
    int sid = (blockIdx.x & 7) * 64 + (blockIdx.x >> 3);
    int b = sid >> 8; int qbase = (sid & 255) * 32;

    {   // stage w2 frags once per block (32 KB)
        const int4* s2 = (const int4*)w2f;  int4* d2 = (int4*)w2B;
        #pragma unroll
        for (int i = 0; i < 4; ++i) d2[t + i*512] = s2[t + i*512];
    }
    __syncthreads();

    int c16 = lane & 15, g = lane >> 4, rowbase = g*4;
    ushort_t* hb = h1b[wid];
    const vshort8* pwBv = (const vshort8*)pwf;       // global, L1-resident
    const vshort8* w2Bv = (const vshort8*)w2B;
    const vfloat4 vzero = (vfloat4){0.f, 0.f, 0.f, 0.f};

    // query-invariant hoists (per-lane): 40 regs
    float pw32r[16], c1r[8], hgr[8], vgr[8];
    #pragma unroll
    for (int n = 0; n < 16; ++n) pw32r[n] = pw32_[n*16 + c16];
    #pragma unroll
    for (int n = 0; n < 8; ++n) {
        c1r[n] = c1_[b*128 + n*16 + c16];
        hgr[n] = h2g_[b*128 + n*16 + c16];
        vgr[n] = vg_[b*128 + n*16 + c16];
    }

    #pragma unroll 1
    for (int qi = 0; qi < 4; ++qi) {
        int q = qbase + wid*4 + qi;                  // sorted index
        float2 qp = qsxy[b*NQ + q];
        float xq = qp.x, yq = qp.y;
        int qorig = qsidx[b*NQ + q];
        int idxrow = knn_idx[(b*NQ + q)*KNN + c16];
        const float* p = xyz + (b*NPTS + idxrow)*3;
        float pd0 = xq - p[0], pd1 = yq - p[1], pd2 = p[2];
        int idxr[4];
        #pragma unroll
        for (int r = 0; r < 4; ++r) idxr[r] = __shfl(idxrow, rowbase + r);

        // emb A-fragment in registers: k = g*8 + j
        vshort8 eh;
        int k0 = g*8;
        #pragma unroll
        for (int j = 0; j < 8; ++j) {
            int k = k0 + j;
            float v;
            if (k < 3) {
                v = (k == 0) ? pd0 : (k == 1 ? pd1 : pd2);
            } else {
                int m = k - 3; int fi = m / 6; int rem = m - fi*6;
                int comp = (rem < 3) ? rem : rem - 3;
                float pdc = (comp == 0) ? pd0 : (comp == 1 ? pd1 : pd2);
                float fr = (fi == 0) ? 1.0f : (fi == 1) ? 8.75f : (fi == 2) ? 16.5f
                         : (fi == 3) ? 24.25f : 32.0f;
                float arg = pdc * fr;
                v = (rem < 3) ? __sinf(arg) : __cosf(arg);
            }
            eh[j] = (short)bf16_rne(v);
        }
        float c32 = __cosf(32.0f * pd2);
        float c32r[4];
        #pragma unroll
        for (int r = 0; r < 4; ++r) c32r[r] = __shfl(c32, rowbase + r);

        // K1p gather prefetch (transient: dies at end of pe1 phase)
        float k1v[4][8];
        #pragma unroll
        for (int r = 0; r < 4; ++r) {
            const float* kp = K1p + ((b*NPTS + idxr[r]) << 7) + c16;
            #pragma unroll
            for (int n = 0; n < 8; ++n) k1v[r][n] = kp[n*16];
        }

        // pe1 + h1 epilogue, one n at a time (acc1 live = 4 regs)
        #pragma unroll
        for (int n = 0; n < 8; ++n) {
            vfloat4 a = __builtin_amdgcn_mfma_f32_16x16x32_bf16(
                eh, pwBv[n*64 + lane], vzero, 0, 0, 0);
            int col = n*16 + c16;
            int s = col >> 5;
            int lp = ((col >> 3) & 3) << 4;
            int j = c16 & 7;
            #pragma unroll
            for (int r = 0; r < 4; ++r) {
                float h = c1r[n] - k1v[r][n] + fmaf(c32r[r], pw32r[n], a[r]);
                h = fmaxf(h, 0.f);
                hb[s*512 + (lp | (rowbase + r))*8 + j] = bf16_rne(h);
            }
        }
        asm volatile("s_waitcnt lgkmcnt(0)" ::: "memory");
        __builtin_amdgcn_sched_barrier(0);

        // GEMM2: [16x128]@[128x128], single bf16
        vfloat4 acc2[8];
        #pragma unroll
        for (int n = 0; n < 8; ++n) acc2[n] = vzero;
        #pragma unroll
        for (int s = 0; s < 4; ++s) {
            vshort8 ah = ((const vshort8*)hb)[s*64 + lane];
            #pragma unroll
            for (int n = 0; n < 8; ++n) {
                vshort8 bh = w2Bv[(n*4 + s)*64 + lane];
                acc2[n] = __builtin_amdgcn_mfma_f32_16x16x32_bf16(ah, bh, acc2[n], 0, 0, 0);
            }
        }

        // softmax over 17 slots, pe2 computed per-n, Vp gathers depth-1 pipelined
        const float* vbase[4];
        #pragma unroll
        for (int r = 0; r < 4; ++r) vbase[r] = Vp + ((b*NPTS + idxr[r]) << 7) + c16;
        float vvp[4];
        #pragma unroll
        for (int r = 0; r < 4; ++r) vvp[r] = vbase[r][0];

        #pragma unroll
        for (int n = 0; n < 8; ++n) {
            float vvc[4];
            #pragma unroll
            for (int r = 0; r < 4; ++r) vvc[r] = vvp[r];
            if (n < 7) {
                #pragma unroll
                for (int r = 0; r < 4; ++r) vvp[r] = vbase[r][(n+1)*16];
            }
            vfloat4 ap = __builtin_amdgcn_mfma_f32_16x16x32_bf16(
                eh, pwBv[(8 + n)*64 + lane], vzero, 0, 0, 0);
            #pragma unroll
            for (int r = 0; r < 4; ++r) ap[r] = fmaf(c32r[r], pw32r[8 + n], ap[r]);

            float hg = hgr[n];
            vfloat4 a2 = acc2[n];
            float mx = fmaxf(fmaxf(a2[0], a2[1]), fmaxf(a2[2], a2[3]));
            mx = fmaxf(mx, __shfl_xor(mx, 16));
            mx = fmaxf(mx, __shfl_xor(mx, 32));
            mx = fmaxf(mx, hg);
            float sum = 0.f, num = 0.f;
            #pragma unroll
            for (int r = 0; r < 4; ++r) {
                float ev = __expf(a2[r] - mx);
                float v = vvc[r] + ap[r];
                sum += ev;
                num = fmaf(ev, v, num);
            }
            sum += __shfl_xor(sum, 16); sum += __shfl_xor(sum, 32);
            num += __shfl_xor(num, 16); num += __shfl_xor(num, 32);
            float eg = __expf(hg - mx);
            sum += eg;
            num = fmaf(eg, vgr[n], num);
            if (g == 0) out[(b*NQ + qorig)*128 + n*16 + c16] = num / sum;
        }
    }
}

extern "C" void kernel_launch(void* const* d_in, const int* in_sizes, int n_in,
                              void* d_out, int out_size, void* d_ws, size_t ws_size,
                              hipStream_t stream) {
    const float* xyz_q  = (const float*)d_in[0];
    const float* lat    = (const float*)d_in[1];
    const float* xyz    = (const float*)d_in[2];
    const float* points = (const float*)d_in[3];
    const float* w_qs   = (const float*)d_in[4];
    const float* w_ks   = (const float*)d_in[5];
    const float* w_vs   = (const float*)d_in[6];
    const float* w_kg   = (const float*)d_in[7];
    const float* w_vg   = (const float*)d_in[8];
    const float* g_w1   = (const float*)d_in[9];
    const float* g_b1   = (const float*)d_in[10];
    const float* g_w2   = (const float*)d_in[11];
    const float* g_b2   = (const float*)d_in[12];  // cancels under softmax
    const float* pe_w   = (const float*)d_in[13];
    const float* pe_b   = (const float*)d_in[14];
    float* out = (float*)d_out;
    (void)g_b2;

    float* ws   = (float*)d_ws;
    float* Vp   = ws;                          // 2*4096*128
    float* K1p  = Vp  + NB*NPTS*DIM;           // 2*4096*128
    float* Wk1  = K1p + NB*NPTS*DIM;           // 128*128
    float* pwc  = Wk1 + DIM*DIM;               // 64*256
    float* c1   = pwc + 64*256;                // 256
    float* vg   = c1  + NB*DIM;                // 256
    float* h2g  = vg  + NB*DIM;                // 256
    int*   knn  = (int*)(h2g + NB*DIM);        // 2*8192*16
    ushort_t* pwf = (ushort_t*)(knn + NB*NQ*KNN);   // 16 KB
    ushort_t* w2f = pwf + 16*64*8;                  // 32 KB
    int* cellcnt  = (int*)(w2f + 32*64*8);          // 2*1024   (zeroed)
    int* qcnt     = cellcnt + NB*NCELL;             // 2*1024   (zeroed, adjacent)
    int* cellstart = qcnt + NB*NCELL;               // 2*1025
    int* cursor    = cellstart + NB*(NCELL+1);      // 2*1024
    int* qstart    = cursor + NB*NCELL;             // 2*1025
    int* qcursor   = qstart + NB*(NCELL+1);         // 2*1024
    int* sidx      = qcursor + NB*NCELL;            // 2*4096
    float2* sxy    = (float2*)(sidx + NB*NPTS);     // 2*4096 float2
    int* qsidx     = (int*)(sxy + NB*NPTS);         // 2*8192
    float2* qsxy   = (float2*)(qsidx + NB*NQ);      // 2*8192 float2

    hipMemsetAsync(cellcnt, 0, 2*NB*NCELL*sizeof(int), stream);  // cellcnt + qcnt
    pre1_k<<<224, 256, 0, stream>>>(w_ks, g_w1, pe_w, xyz, xyz_q,
                                    Wk1, pwc, cellcnt, qcnt);
    pre2_k<<<17, 256, 0, stream>>>(pwc, g_w2, cellcnt, qcnt,
                                   lat, w_qs, w_kg, w_vg, g_w1, g_b1, pe_b,
                                   pwf, w2f, cellstart, cursor, qstart, qcursor,
                                   c1, vg, h2g);
    pre3_k<<<608, 256, 0, stream>>>(points, Wk1, w_vs, pe_b, xyz, xyz_q,
                                    cursor, qcursor, K1p, Vp, sxy, sidx, qsxy, qsidx);
    knn_k<<<NB*NQ/4, 256, 0, stream>>>(qsxy, sxy, sidx, cellstart, knn);
    fuse_k<<<NB*NQ/32, 512, 0, stream>>>(qsxy, qsidx, xyz, K1p, Vp, knn, c1, vg, h2g,
                                         pwc + 32*256, pwf, w2f, out);
}